// Round 2
// baseline (773.709 us; speedup 1.0000x reference)
//
#include <hip/hip_runtime.h>
#include <hip/hip_bf16.h>

#define N_NODES 50000
#define N_EDGES 800000
#define F_IN 128
#define HEADS 8
#define HID 16
#define HC 128  // HEADS*HID

__device__ __forceinline__ float bf2f(unsigned short u) {
  union { unsigned int i; float f; } v;
  v.i = (unsigned int)u << 16;
  return v.f;
}

// ---------------------------------------------------------------------------
// K1: fused dual GEMM  xl = x@Wl + bl, xr = x@Wr + br  -> stored as bf16
// ---------------------------------------------------------------------------
__global__ __launch_bounds__(256) void k_gemm(
    const float* __restrict__ x,
    const float* __restrict__ Wl, const float* __restrict__ bl,
    const float* __restrict__ Wr, const float* __restrict__ br,
    __hip_bfloat16* __restrict__ xl, __hip_bfloat16* __restrict__ xr) {
  __shared__ float xs[16 * 128];
  const int t = threadIdx.x;
  const int block_row = blockIdx.x * 16;

  const float4* xsrc = (const float4*)(x + (size_t)block_row * F_IN);
  float4* xd = (float4*)xs;
  xd[t] = xsrc[t];
  xd[t + 256] = xsrc[t + 256];
  __syncthreads();

  const int col = t & 127;
  const bool right = t >= 128;
  const float* __restrict__ W = right ? Wr : Wl;
  const float* __restrict__ bv = right ? br : bl;

  float acc[16];
#pragma unroll
  for (int r = 0; r < 16; ++r) acc[r] = 0.f;

  for (int k = 0; k < 128; k += 4) {
    const float w0 = W[(k + 0) * HC + col];
    const float w1 = W[(k + 1) * HC + col];
    const float w2 = W[(k + 2) * HC + col];
    const float w3 = W[(k + 3) * HC + col];
#pragma unroll
    for (int r = 0; r < 16; ++r) {
      const float4 xv = *((const float4*)(xs + r * 128 + k));  // wave-uniform LDS broadcast
      acc[r] = fmaf(xv.x, w0, acc[r]);
      acc[r] = fmaf(xv.y, w1, acc[r]);
      acc[r] = fmaf(xv.z, w2, acc[r]);
      acc[r] = fmaf(xv.w, w3, acc[r]);
    }
  }
  const float b = bv[col];
  __hip_bfloat16* __restrict__ dst = right ? xr : xl;
#pragma unroll
  for (int r = 0; r < 16; ++r)
    dst[(size_t)(block_row + r) * HC + col] = __float2bfloat16(acc[r] + b);
}

// ---------------------------------------------------------------------------
// K2a: degree histogram over dst
// ---------------------------------------------------------------------------
__global__ __launch_bounds__(256) void k_deg(const int* __restrict__ eidx,
                                             int* __restrict__ deg) {
  const int e = blockIdx.x * 256 + threadIdx.x;
  if (e < N_EDGES) atomicAdd(&deg[eidx[N_EDGES + e]], 1);
}

// ---------------------------------------------------------------------------
// K2b: single-block scan of degrees -> offs[0..N_NODES]
// thread-serial chunks (49/node) + one 1024-wide Kogge-Stone LDS scan
// ---------------------------------------------------------------------------
__global__ __launch_bounds__(1024) void k_scan(const int* __restrict__ deg,
                                               int* __restrict__ offs) {
  __shared__ int sm[1024];
  const int t = threadIdx.x;
  const int per = (N_NODES + 1023) / 1024;  // 49
  const int base = t * per;
  int s = 0;
  for (int i = 0; i < per; ++i) {
    const int idx = base + i;
    if (idx < N_NODES) s += deg[idx];
  }
  sm[t] = s;
  __syncthreads();
  for (int off = 1; off < 1024; off <<= 1) {
    const int add = (t >= off) ? sm[t - off] : 0;
    __syncthreads();
    sm[t] += add;
    __syncthreads();
  }
  int excl = sm[t] - s;
  for (int i = 0; i < per; ++i) {
    const int idx = base + i;
    if (idx < N_NODES) {
      offs[idx] = excl;
      excl += deg[idx];
    }
  }
  if (t == 1023) offs[N_NODES] = sm[1023];
}

// ---------------------------------------------------------------------------
// K2c: scatter packed edge records {src, ea.x, ea.y, 0} into CSR order
// ---------------------------------------------------------------------------
__global__ __launch_bounds__(256) void k_scatter(
    const int* __restrict__ eidx, const float* __restrict__ eattr,
    const int* __restrict__ offs, int* __restrict__ cursor,
    int4* __restrict__ epack) {
  const int e = blockIdx.x * 256 + threadIdx.x;
  if (e < N_EDGES) {
    const int src = eidx[e];
    const int d = eidx[N_EDGES + e];
    const float2 ea = *(const float2*)(eattr + (size_t)e * 2);
    const int pos = atomicAdd(&cursor[d], 1);
    epack[offs[d] + pos] =
        make_int4(src, __float_as_int(ea.x), __float_as_int(ea.y), 0);
  }
}

// ---------------------------------------------------------------------------
// K3: fused per-node  logit -> exp -> weighted-aggregate -> BN partial stats
// One 64-lane wave per node; lane owns channels (2*lane, 2*lane+1), head=lane>>3.
// out[n][c] = (sum_e exp(logit_e,h) * xl[src_e][c]) / (sum_e exp(logit_e,h))
// ---------------------------------------------------------------------------
__global__ __launch_bounds__(256) void k_fused(
    const int* __restrict__ offs, const int4* __restrict__ epack,
    const __hip_bfloat16* __restrict__ xl, const __hip_bfloat16* __restrict__ xr,
    const float* __restrict__ We, const float* __restrict__ be,
    const float* __restrict__ att,
    float* __restrict__ outp, float* __restrict__ stats) {
  const int wave = threadIdx.x >> 6;
  const int lane = threadIdx.x & 63;
  const int node = blockIdx.x * 4 + wave;
  const int c0 = lane * 2;

  // per-lane constants (att is (8,16) flat -> index == channel)
  const float w0a = We[c0],      w0b = We[c0 + 1];
  const float w1a = We[HC + c0], w1b = We[HC + c0 + 1];
  const float bea = be[c0],      beb = be[c0 + 1];
  const float ata = att[c0],     atb = att[c0 + 1];

  float o0 = 0.f, o1 = 0.f;
  if (node < N_NODES) {
    const unsigned int xrv = *(const unsigned int*)(xr + (size_t)node * HC + c0);
    const float xra = bf2f((unsigned short)xrv);
    const float xrb = bf2f((unsigned short)(xrv >> 16));

    const int beg = offs[node], end = offs[node + 1];
    float acc0 = 0.f, acc1 = 0.f, dn = 0.f;
    for (int k = beg; k < end; ++k) {
      const int4 rec = epack[k];            // wave-uniform sequential 16B
      const int src = rec.x;
      const float eax = __int_as_float(rec.y);
      const float eay = __int_as_float(rec.z);
      const unsigned int xv = *(const unsigned int*)(xl + (size_t)src * HC + c0);
      const float x0 = bf2f((unsigned short)xv);
      const float x1 = bf2f((unsigned short)(xv >> 16));
      float m0 = x0 + xra + fmaf(eax, w0a, fmaf(eay, w1a, bea));
      float m1 = x1 + xrb + fmaf(eax, w0b, fmaf(eay, w1b, beb));
      m0 = m0 > 0.f ? m0 : 0.2f * m0;
      m1 = m1 > 0.f ? m1 : 0.2f * m1;
      float p = fmaf(m0, ata, m1 * atb);
      p += __shfl_xor(p, 1);
      p += __shfl_xor(p, 2);
      p += __shfl_xor(p, 4);                // 8-lane head-group reduce
      const float exv = __expf(p);
      dn += exv;
      acc0 = fmaf(exv, x0, acc0);
      acc1 = fmaf(exv, x1, acc1);
    }
    const float inv = dn > 0.f ? 1.0f / dn : 0.f;
    o0 = acc0 * inv;
    o1 = acc1 * inv;
    float2 o; o.x = o0; o.y = o1;
    *((float2*)(outp + (size_t)node * HC) + lane) = o;
  }

  // BN partial stats: block-level reduce (4 waves x 128 ch), then global atomics
  __shared__ float ssum[4 * 128];
  __shared__ float ssq[4 * 128];
  ssum[wave * 128 + c0]     = o0;
  ssum[wave * 128 + c0 + 1] = o1;
  ssq[wave * 128 + c0]      = o0 * o0;
  ssq[wave * 128 + c0 + 1]  = o1 * o1;
  __syncthreads();
  if (threadIdx.x < 128) {
    const int c = threadIdx.x;
    const float s1 = ssum[c] + ssum[128 + c] + ssum[256 + c] + ssum[384 + c];
    const float s2 = ssq[c] + ssq[128 + c] + ssq[256 + c] + ssq[384 + c];
    atomicAdd(&stats[c], s1);
    atomicAdd(&stats[128 + c], s2);
  }
}

// ---------------------------------------------------------------------------
// K4: BatchNorm (batch stats) + LeakyReLU(0.01), in place on outp
// ---------------------------------------------------------------------------
__global__ __launch_bounds__(256) void k_bn(const float* __restrict__ stats,
                                            const float* __restrict__ gamma,
                                            const float* __restrict__ beta,
                                            float* __restrict__ outp) {
  const int i = blockIdx.x * 256 + threadIdx.x;
  if (i >= N_NODES * HC) return;
  const int c = i & 127;
  const float mean = stats[c] * (1.0f / N_NODES);
  const float var = stats[128 + c] * (1.0f / N_NODES) - mean * mean;
  const float rstd = rsqrtf(var + 1e-5f);
  float v = (outp[i] - mean) * rstd * gamma[c] + beta[c];
  outp[i] = v > 0.f ? v : 0.01f * v;
}

// ---------------------------------------------------------------------------
extern "C" void kernel_launch(void* const* d_in, const int* in_sizes, int n_in,
                              void* d_out, int out_size, void* d_ws, size_t ws_size,
                              hipStream_t stream) {
  const float* x     = (const float*)d_in[0];
  const int*   eidx  = (const int*)d_in[1];
  const float* eattr = (const float*)d_in[2];
  const float* Wl    = (const float*)d_in[3];
  const float* bl    = (const float*)d_in[4];
  const float* Wr    = (const float*)d_in[5];
  const float* br    = (const float*)d_in[6];
  const float* We    = (const float*)d_in[7];
  const float* be    = (const float*)d_in[8];
  const float* att   = (const float*)d_in[9];
  // d_in[10] = bias: cancels exactly in BatchNorm mean subtraction -> unused
  const float* gamma = (const float*)d_in[11];
  const float* beta  = (const float*)d_in[12];
  float* out = (float*)d_out;

  char* ws = (char*)d_ws;
  size_t off = 0;
  auto alloc = [&](size_t bytes) {
    size_t o = off;
    off = (off + bytes + 15) & ~size_t(15);
    return o;
  };
  // zero-initialized region first
  const size_t o_deg   = alloc((size_t)(N_NODES + 1) * 4);
  const size_t o_cur   = alloc((size_t)N_NODES * 4);
  const size_t o_stats = alloc(256 * 4);
  const size_t zero_bytes = off;
  // non-zeroed scratch
  const size_t o_offs = alloc((size_t)(N_NODES + 1) * 4);
  const size_t o_ep   = alloc((size_t)N_EDGES * 16);
  const size_t o_xl   = alloc((size_t)N_NODES * HC * 2);
  const size_t o_xr   = alloc((size_t)N_NODES * HC * 2);
  (void)ws_size; (void)in_sizes; (void)n_in; (void)out_size;

  int*   deg   = (int*)(ws + o_deg);
  int*   cur   = (int*)(ws + o_cur);
  float* stats = (float*)(ws + o_stats);
  int*   offs  = (int*)(ws + o_offs);
  int4*  epack = (int4*)(ws + o_ep);
  __hip_bfloat16* xl = (__hip_bfloat16*)(ws + o_xl);
  __hip_bfloat16* xr = (__hip_bfloat16*)(ws + o_xr);

  hipMemsetAsync(ws, 0, zero_bytes, stream);

  k_gemm<<<N_NODES / 16, 256, 0, stream>>>(x, Wl, bl, Wr, br, xl, xr);
  k_deg<<<(N_EDGES + 255) / 256, 256, 0, stream>>>(eidx, deg);
  k_scan<<<1, 1024, 0, stream>>>(deg, offs);
  k_scatter<<<(N_EDGES + 255) / 256, 256, 0, stream>>>(eidx, eattr, offs, cur, epack);
  k_fused<<<(N_NODES + 3) / 4, 256, 0, stream>>>(offs, epack, xl, xr, We, be, att,
                                                 out, stats);
  k_bn<<<(N_NODES * HC + 255) / 256, 256, 0, stream>>>(stats, gamma, beta, out);
}

// Round 3
// 529.123 us; speedup vs baseline: 1.4622x; 1.4622x over previous
//
#include <hip/hip_runtime.h>
#include <hip/hip_bf16.h>

#define N_NODES 50000
#define N_EDGES 800000
#define F_IN 128
#define HEADS 8
#define HID 16
#define HC 128  // HEADS*HID

__device__ __forceinline__ float bf2f(unsigned short u) {
  union { unsigned int i; float f; } v;
  v.i = (unsigned int)u << 16;
  return v.f;
}

// ---------------------------------------------------------------------------
// K1: fused dual GEMM  xl = x@Wl + bl, xr = x@Wr + br  -> stored as bf16
// ---------------------------------------------------------------------------
__global__ __launch_bounds__(256) void k_gemm(
    const float* __restrict__ x,
    const float* __restrict__ Wl, const float* __restrict__ bl,
    const float* __restrict__ Wr, const float* __restrict__ br,
    __hip_bfloat16* __restrict__ xl, __hip_bfloat16* __restrict__ xr) {
  __shared__ float xs[16 * 128];
  const int t = threadIdx.x;
  const int block_row = blockIdx.x * 16;

  const float4* xsrc = (const float4*)(x + (size_t)block_row * F_IN);
  float4* xd = (float4*)xs;
  xd[t] = xsrc[t];
  xd[t + 256] = xsrc[t + 256];
  __syncthreads();

  const int col = t & 127;
  const bool right = t >= 128;
  const float* __restrict__ W = right ? Wr : Wl;
  const float* __restrict__ bv = right ? br : bl;

  float acc[16];
#pragma unroll
  for (int r = 0; r < 16; ++r) acc[r] = 0.f;

  for (int k = 0; k < 128; k += 4) {
    const float w0 = W[(k + 0) * HC + col];
    const float w1 = W[(k + 1) * HC + col];
    const float w2 = W[(k + 2) * HC + col];
    const float w3 = W[(k + 3) * HC + col];
#pragma unroll
    for (int r = 0; r < 16; ++r) {
      const float4 xv = *((const float4*)(xs + r * 128 + k));  // wave-uniform LDS broadcast
      acc[r] = fmaf(xv.x, w0, acc[r]);
      acc[r] = fmaf(xv.y, w1, acc[r]);
      acc[r] = fmaf(xv.z, w2, acc[r]);
      acc[r] = fmaf(xv.w, w3, acc[r]);
    }
  }
  const float b = bv[col];
  __hip_bfloat16* __restrict__ dst = right ? xr : xl;
#pragma unroll
  for (int r = 0; r < 16; ++r)
    dst[(size_t)(block_row + r) * HC + col] = __float2bfloat16(acc[r] + b);
}

// ---------------------------------------------------------------------------
// K2a: degree histogram over dst
// ---------------------------------------------------------------------------
__global__ __launch_bounds__(256) void k_deg(const int* __restrict__ eidx,
                                             int* __restrict__ deg) {
  const int e = blockIdx.x * 256 + threadIdx.x;
  if (e < N_EDGES) atomicAdd(&deg[eidx[N_EDGES + e]], 1);
}

// ---------------------------------------------------------------------------
// K2b: single-block scan of degrees -> offs[0..N_NODES]
// ---------------------------------------------------------------------------
__global__ __launch_bounds__(1024) void k_scan(const int* __restrict__ deg,
                                               int* __restrict__ offs) {
  __shared__ int sm[1024];
  const int t = threadIdx.x;
  const int per = (N_NODES + 1023) / 1024;  // 49
  const int base = t * per;
  int s = 0;
  for (int i = 0; i < per; ++i) {
    const int idx = base + i;
    if (idx < N_NODES) s += deg[idx];
  }
  sm[t] = s;
  __syncthreads();
  for (int off = 1; off < 1024; off <<= 1) {
    const int add = (t >= off) ? sm[t - off] : 0;
    __syncthreads();
    sm[t] += add;
    __syncthreads();
  }
  int excl = sm[t] - s;
  for (int i = 0; i < per; ++i) {
    const int idx = base + i;
    if (idx < N_NODES) {
      offs[idx] = excl;
      excl += deg[idx];
    }
  }
  if (t == 1023) offs[N_NODES] = sm[1023];
}

// ---------------------------------------------------------------------------
// K2c: assign CSR slots; record per-edge slot and CSR-ordered src
// ---------------------------------------------------------------------------
__global__ __launch_bounds__(256) void k_scatter(
    const int* __restrict__ eidx, const int* __restrict__ offs,
    int* __restrict__ cursor, int* __restrict__ eslot,
    int* __restrict__ src_csr) {
  const int e = blockIdx.x * 256 + threadIdx.x;
  if (e < N_EDGES) {
    const int src = eidx[e];
    const int d = eidx[N_EDGES + e];
    const int pos = atomicAdd(&cursor[d], 1);
    const int slot = offs[d] + pos;
    eslot[e] = slot;
    src_csr[slot] = src;
  }
}

// ---------------------------------------------------------------------------
// K3: edge-parallel attention. Thread = (edge, head). Computes logit ->
// ex = exp(logit), written at the edge's CSR slot; denom accumulated atomically.
// ---------------------------------------------------------------------------
__global__ __launch_bounds__(256) void k_edge(
    const int* __restrict__ eidx, const float* __restrict__ eattr,
    const int* __restrict__ eslot,
    const float* __restrict__ We, const float* __restrict__ be,
    const float* __restrict__ att,
    const __hip_bfloat16* __restrict__ xl, const __hip_bfloat16* __restrict__ xr,
    float* __restrict__ ex8, float* __restrict__ denom) {
  const int tid = blockIdx.x * 256 + threadIdx.x;
  if (tid >= N_EDGES * HEADS) return;
  const int e = tid >> 3;
  const int h = tid & 7;
  const int src = eidx[e];
  const int dst = eidx[N_EDGES + e];
  const float2 ea = *(const float2*)(eattr + (size_t)e * 2);
  const int slot = eslot[e];

  // 16-channel bf16 slices (32B each), 8 lanes of a head-group cover the row
  union { uint4 v[2]; unsigned int u[8]; } A, B;
  const uint4* xl4 = (const uint4*)(xl + (size_t)src * HC + h * HID);
  const uint4* xr4 = (const uint4*)(xr + (size_t)dst * HC + h * HID);
  A.v[0] = xl4[0]; A.v[1] = xl4[1];
  B.v[0] = xr4[0]; B.v[1] = xr4[1];

  float logit = 0.f;
#pragma unroll
  for (int jj = 0; jj < 4; ++jj) {
    const int c = h * HID + jj * 4;
    const float4 w0 = *(const float4*)(We + c);
    const float4 w1 = *(const float4*)(We + HC + c);
    const float4 bb = *(const float4*)(be + c);
    const float4 av = *(const float4*)(att + c);
    const unsigned int ua0 = A.u[jj * 2], ua1 = A.u[jj * 2 + 1];
    const unsigned int ub0 = B.u[jj * 2], ub1 = B.u[jj * 2 + 1];
    float m0 = bf2f((unsigned short)ua0) + bf2f((unsigned short)ub0) +
               fmaf(ea.x, w0.x, fmaf(ea.y, w1.x, bb.x));
    float m1 = bf2f((unsigned short)(ua0 >> 16)) + bf2f((unsigned short)(ub0 >> 16)) +
               fmaf(ea.x, w0.y, fmaf(ea.y, w1.y, bb.y));
    float m2 = bf2f((unsigned short)ua1) + bf2f((unsigned short)ub1) +
               fmaf(ea.x, w0.z, fmaf(ea.y, w1.z, bb.z));
    float m3 = bf2f((unsigned short)(ua1 >> 16)) + bf2f((unsigned short)(ub1 >> 16)) +
               fmaf(ea.x, w0.w, fmaf(ea.y, w1.w, bb.w));
    m0 = m0 > 0.f ? m0 : 0.2f * m0;
    m1 = m1 > 0.f ? m1 : 0.2f * m1;
    m2 = m2 > 0.f ? m2 : 0.2f * m2;
    m3 = m3 > 0.f ? m3 : 0.2f * m3;
    logit = fmaf(m0, av.x, logit);
    logit = fmaf(m1, av.y, logit);
    logit = fmaf(m2, av.z, logit);
    logit = fmaf(m3, av.w, logit);
  }
  const float exv = __expf(logit);
  ex8[(size_t)slot * HEADS + h] = exv;
  atomicAdd(&denom[(size_t)dst * HEADS + h], exv);
}

// ---------------------------------------------------------------------------
// K4: CSR aggregation, one wave per node, 4-deep double-buffered prefetch.
// out[n][c] = (sum_k ex8[k][h] * xl[src_k][c]) / denom[n][h]
// ---------------------------------------------------------------------------
__global__ __launch_bounds__(256) void k_agg(
    const int* __restrict__ offs, const int* __restrict__ src_csr,
    const float* __restrict__ ex8, const float* __restrict__ denom,
    const __hip_bfloat16* __restrict__ xl, float* __restrict__ outp) {
  const int wave = threadIdx.x >> 6;
  const int lane = threadIdx.x & 63;
  const int node = blockIdx.x * 4 + wave;
  if (node >= N_NODES) return;
  const int head = lane >> 3;
  const int c0 = lane * 2;
  const float dn = denom[(size_t)node * HEADS + head];
  const float inv = dn > 0.f ? 1.0f / dn : 0.f;
  const int beg = offs[node], end = offs[node + 1];

  float s0 = 0.f, s1 = 0.f;
  if (beg < end) {
    const int endm1 = end - 1;
    unsigned int xA[4];
    float eA[4];
#pragma unroll
    for (int j = 0; j < 4; ++j) {
      const int k = beg + j;
      const int kk = k < endm1 ? k : endm1;  // clamp: valid addr, weight zeroed
      const int sidx = src_csr[kk];
      const float ev = ex8[(size_t)kk * HEADS + head];
      xA[j] = *(const unsigned int*)(xl + (size_t)sidx * HC + c0);
      eA[j] = (k < end) ? ev : 0.f;
    }
    for (int k0 = beg;;) {
      const int k1 = k0 + 4;
      const bool more = k1 < end;
      unsigned int xB[4];
      float eB[4];
      if (more) {
#pragma unroll
        for (int j = 0; j < 4; ++j) {
          const int k = k1 + j;
          const int kk = k < endm1 ? k : endm1;
          const int sidx = src_csr[kk];
          const float ev = ex8[(size_t)kk * HEADS + head];
          xB[j] = *(const unsigned int*)(xl + (size_t)sidx * HC + c0);
          eB[j] = (k < end) ? ev : 0.f;
        }
      }
#pragma unroll
      for (int j = 0; j < 4; ++j) {
        s0 = fmaf(eA[j], bf2f((unsigned short)xA[j]), s0);
        s1 = fmaf(eA[j], bf2f((unsigned short)(xA[j] >> 16)), s1);
      }
      if (!more) break;
#pragma unroll
      for (int j = 0; j < 4; ++j) { xA[j] = xB[j]; eA[j] = eB[j]; }
      k0 = k1;
    }
  }
  float2 o;
  o.x = s0 * inv;
  o.y = s1 * inv;
  *((float2*)(outp + (size_t)node * HC) + lane) = o;
}

// ---------------------------------------------------------------------------
// K5: per-channel sum / sumsq over nodes (BatchNorm batch stats)
// ---------------------------------------------------------------------------
__global__ __launch_bounds__(256) void k_stats(const float* __restrict__ outp,
                                               float* __restrict__ stats) {
  const int c = threadIdx.x & 127;
  const int half = threadIdx.x >> 7;
  float s1 = 0.f, s2 = 0.f;
  for (int r = blockIdx.x * 2 + half; r < N_NODES; r += gridDim.x * 2) {
    const float v = outp[(size_t)r * HC + c];
    s1 += v;
    s2 = fmaf(v, v, s2);
  }
  __shared__ float sm[512];
  sm[threadIdx.x] = s1;
  sm[256 + threadIdx.x] = s2;
  __syncthreads();
  if (threadIdx.x < 128) {
    s1 = sm[threadIdx.x] + sm[threadIdx.x + 128];
    s2 = sm[256 + threadIdx.x] + sm[256 + threadIdx.x + 128];
    atomicAdd(&stats[c], s1);
    atomicAdd(&stats[128 + c], s2);
  }
}

// ---------------------------------------------------------------------------
// K6: BatchNorm (batch stats) + LeakyReLU(0.01), in place on outp
// ---------------------------------------------------------------------------
__global__ __launch_bounds__(256) void k_bn(const float* __restrict__ stats,
                                            const float* __restrict__ gamma,
                                            const float* __restrict__ beta,
                                            float* __restrict__ outp) {
  const int i = blockIdx.x * 256 + threadIdx.x;
  if (i >= N_NODES * HC) return;
  const int c = i & 127;
  const float mean = stats[c] * (1.0f / N_NODES);
  const float var = stats[128 + c] * (1.0f / N_NODES) - mean * mean;
  const float rstd = rsqrtf(var + 1e-5f);
  float v = (outp[i] - mean) * rstd * gamma[c] + beta[c];
  outp[i] = v > 0.f ? v : 0.01f * v;
}

// ---------------------------------------------------------------------------
extern "C" void kernel_launch(void* const* d_in, const int* in_sizes, int n_in,
                              void* d_out, int out_size, void* d_ws, size_t ws_size,
                              hipStream_t stream) {
  const float* x     = (const float*)d_in[0];
  const int*   eidx  = (const int*)d_in[1];
  const float* eattr = (const float*)d_in[2];
  const float* Wl    = (const float*)d_in[3];
  const float* bl    = (const float*)d_in[4];
  const float* Wr    = (const float*)d_in[5];
  const float* br    = (const float*)d_in[6];
  const float* We    = (const float*)d_in[7];
  const float* be    = (const float*)d_in[8];
  const float* att   = (const float*)d_in[9];
  // d_in[10] = bias: cancels exactly in BatchNorm mean subtraction -> unused
  const float* gamma = (const float*)d_in[11];
  const float* beta  = (const float*)d_in[12];
  float* out = (float*)d_out;

  char* ws = (char*)d_ws;
  size_t off = 0;
  auto alloc = [&](size_t bytes) {
    size_t o = off;
    off = (off + bytes + 15) & ~size_t(15);
    return o;
  };
  // zero-initialized region first
  const size_t o_deg   = alloc((size_t)(N_NODES + 1) * 4);
  const size_t o_cur   = alloc((size_t)N_NODES * 4);
  const size_t o_denom = alloc((size_t)N_NODES * HEADS * 4);
  const size_t o_stats = alloc(256 * 4);
  const size_t zero_bytes = off;
  // non-zeroed scratch
  const size_t o_offs = alloc((size_t)(N_NODES + 1) * 4);
  const size_t o_slot = alloc((size_t)N_EDGES * 4);
  const size_t o_srcc = alloc((size_t)N_EDGES * 4);
  const size_t o_ex   = alloc((size_t)N_EDGES * HEADS * 4);
  const size_t o_xl   = alloc((size_t)N_NODES * HC * 2);
  const size_t o_xr   = alloc((size_t)N_NODES * HC * 2);
  (void)ws_size; (void)in_sizes; (void)n_in; (void)out_size;

  int*   deg     = (int*)(ws + o_deg);
  int*   cur     = (int*)(ws + o_cur);
  float* denom   = (float*)(ws + o_denom);
  float* stats   = (float*)(ws + o_stats);
  int*   offs    = (int*)(ws + o_offs);
  int*   eslot   = (int*)(ws + o_slot);
  int*   src_csr = (int*)(ws + o_srcc);
  float* ex8     = (float*)(ws + o_ex);
  __hip_bfloat16* xl = (__hip_bfloat16*)(ws + o_xl);
  __hip_bfloat16* xr = (__hip_bfloat16*)(ws + o_xr);

  hipMemsetAsync(ws, 0, zero_bytes, stream);

  k_gemm<<<N_NODES / 16, 256, 0, stream>>>(x, Wl, bl, Wr, br, xl, xr);
  k_deg<<<(N_EDGES + 255) / 256, 256, 0, stream>>>(eidx, deg);
  k_scan<<<1, 1024, 0, stream>>>(deg, offs);
  k_scatter<<<(N_EDGES + 255) / 256, 256, 0, stream>>>(eidx, offs, cur, eslot, src_csr);
  k_edge<<<(N_EDGES * HEADS + 255) / 256, 256, 0, stream>>>(
      eidx, eattr, eslot, We, be, att, xl, xr, ex8, denom);
  k_agg<<<(N_NODES + 3) / 4, 256, 0, stream>>>(offs, src_csr, ex8, denom, xl, out);
  k_stats<<<256, 256, 0, stream>>>(out, stats);
  k_bn<<<(N_NODES * HC + 255) / 256, 256, 0, stream>>>(stats, gamma, beta, out);
}